// Round 10
// baseline (163.199 us; speedup 1.0000x reference)
//
#include <hip/hip_runtime.h>
#include <math.h>

#define H 768
#define S 256
#define NB 4      // batch
#define TOPK 4
#define L 4
#define NH 8      // biaffine h-split chunks (96 h each)

// 2/ln2: tanh(x) = 1 - 2/(2^(C*x)+1)
#define CSCALE 2.8853900817779268f

typedef __bf16 bf16x8 __attribute__((ext_vector_type(8)));
typedef __bf16 bf16x4 __attribute__((ext_vector_type(4)));
typedef float floatx4 __attribute__((ext_vector_type(4)));

// Native-rate transcendentals. exp2f()/expf() without -ffast-math are OCML
// precise libcalls (~20 VALU ops) -- round 3's lesson.
__device__ __forceinline__ float exp2_native(float x) {
#if __has_builtin(__builtin_amdgcn_exp2f)
  return __builtin_amdgcn_exp2f(x);
#else
  float r; asm("v_exp_f32 %0, %1" : "=v"(r) : "v"(x)); return r;
#endif
}
__device__ __forceinline__ float rcp_native(float x) {
#if __has_builtin(__builtin_amdgcn_rcpf)
  return __builtin_amdgcn_rcpf(x);
#else
  float r; asm("v_rcp_f32 %0, %1" : "=v"(r) : "v"(x)); return r;
#endif
}

// tanh for the hidden epilogue (__expf is native-rate; passing since round 2)
__device__ __forceinline__ float fast_tanh(float x) {
  float cx = fminf(15.f, fmaxf(-15.f, x));
  float e = __expf(cx + cx);
  return __fdividef(e - 1.f, e + 1.f);
}

// ---------------------------------------------------------------------------
// Stage 0 (one-shot conversion -- round 8's in-GEMM fusion did this work 32x
// redundantly per B-row; that was mega's hidden ~20+ us):
// pooled -> (Ah,Al) hi/lo bf16; concat(Wa,Ua) -> (Wh,Wl) hi/lo;
// dense_w -> Drow bf16 re-laid as 1536 rows of length 768:
//   Drow[o] = dense_w[o][0:768] (dep), Drow[768+o] = dense_w[o][768:1536] (head)
__global__ __launch_bounds__(256) void cvt_kernel(
    const float* __restrict__ pooled, const float* __restrict__ Wa_w,
    const float* __restrict__ Ua_w, const float* __restrict__ dense_w,
    __bf16* __restrict__ Ah, __bf16* __restrict__ Al,
    __bf16* __restrict__ Wh, __bf16* __restrict__ Wl,
    __bf16* __restrict__ Drow) {
  const int NA4 = (NB * S * H) / 4;       // 196608
  const int NW4 = (2 * H * H) / 4;        // 294912 (Wa then Ua)
  const int NWa4 = (H * H) / 4;           // 147456
  const int ND4 = (H * 2 * H) / 4;        // 294912
  int i = blockIdx.x * 256 + threadIdx.x;
  if (i >= NA4 + NW4 + ND4) return;
  if (i >= NA4 + NW4) {  // dense_w -> Drow (hi only), dep/head split
    int w = i - NA4 - NW4;
    int o = w / 384;         // 384 float4 per source row of 1536
    int k = (w - o * 384) * 4;
    float4 v = ((const float4*)dense_w)[w];
    union { __bf16 h[4]; ushort4 u; } tmp;
    tmp.h[0] = (__bf16)v.x; tmp.h[1] = (__bf16)v.y;
    tmp.h[2] = (__bf16)v.z; tmp.h[3] = (__bf16)v.w;
    int row = (k < H) ? o : (H + o);
    int col = (k < H) ? k : (k - H);
    *(ushort4*)(Drow + (size_t)row * H + col) = tmp.u;
    return;
  }
  float4 v;
  __bf16 *hi, *lo;
  if (i < NA4) {
    v = ((const float4*)pooled)[i];
    hi = Ah + i * 4; lo = Al + i * 4;
  } else {
    int w = i - NA4;
    v = (w < NWa4) ? ((const float4*)Wa_w)[w] : ((const float4*)Ua_w)[w - NWa4];
    hi = Wh + (size_t)w * 4; lo = Wl + (size_t)w * 4;
  }
  union { __bf16 h[4]; ushort4 u; } a, b;
  float f[4] = {v.x, v.y, v.z, v.w};
#pragma unroll
  for (int k = 0; k < 4; ++k) {
    __bf16 h = (__bf16)f[k];
    a.h[k] = h;
    b.h[k] = (__bf16)(f[k] - (float)h);
  }
  *(ushort4*)hi = a.u;
  *(ushort4*)lo = b.u;
}

// ---------------------------------------------------------------------------
// Stage 1 (single GEMM, bf16 sources, software-pipelined): C = pooled @ B^T,
// B rows 0..1535 = concat(Wa,Ua) hi/lo (3-term split -> hij, CSCALE-scaled);
// 1536..2303 = dense dep half (+dense_b -> dpb); 2304..3071 = head (-> hpb).
// Staging is now pure bf16 vector copies (no conversion VALU); double-buffered
// LDS, single barrier/iter, next iter's loads prefetched after the barrier.
__global__ __launch_bounds__(256) void mega_mfma(
    const __bf16* __restrict__ Ah, const __bf16* __restrict__ Al,
    const __bf16* __restrict__ Wh, const __bf16* __restrict__ Wl,
    const __bf16* __restrict__ Drow, const float* __restrict__ Wa_b,
    const float* __restrict__ Ua_b, const float* __restrict__ dense_b,
    float* __restrict__ hij, __bf16* __restrict__ dpb,
    __bf16* __restrict__ hpb) {
  __shared__ __align__(16) __bf16 Ahs[2][32][40];
  __shared__ __align__(16) __bf16 Als[2][32][40];
  __shared__ __align__(16) __bf16 Bhs[2][128][40];
  __shared__ __align__(16) __bf16 Bls[2][128][40];   // 51.2 KB -> 3 blocks/CU
  const int m0 = blockIdx.x * 32;
  const int g = blockIdx.y;                       // swizzle: even->proj, odd->dense
  const int ng = (g & 1) ? (12 + (g >> 1)) : (g >> 1);
  const int n0 = ng * 128;
  const bool isproj = (ng < 12);
  const int t = threadIdx.x;
  // A staging: 32 rows x 32 k bf16; thread: row t>>3, 4 bf16 at (t&7)*4
  const int arow = t >> 3;
  const int ka = (t & 7) * 4;
  const __bf16* Arh = Ah + (size_t)(m0 + arow) * H;
  const __bf16* Arl = Al + (size_t)(m0 + arow) * H;
  // B staging: 128 rows x 32 k; thread: row t>>1, 16 bf16 at (t&1)*16
  const int brow = t >> 1;
  const int kb = (t & 1) * 16;
  const int ncol = n0 + brow;
  const __bf16* Brh = isproj ? (Wh + (size_t)ncol * H)
                             : (Drow + (size_t)(ncol - 2 * H) * H);
  const __bf16* Brl = Wl + (size_t)(isproj ? ncol : brow) * H;  // unused if !isproj
  const int lane = t & 63;
  const int wave = t >> 6;
  const int wn = wave * 32;
  const int fm = lane & 15;
  const int quad = lane >> 4;
  floatx4 acc[2][2] = {};

  // prologue: prefetch kc = 0
  ushort4 a_h = *(const ushort4*)&Arh[ka];
  ushort4 a_l = *(const ushort4*)&Arl[ka];
  bf16x8 b_h0 = *(const bf16x8*)&Brh[kb];
  bf16x8 b_h1 = *(const bf16x8*)&Brh[kb + 8];
  bf16x8 b_l0 = {}, b_l1 = {};
  if (isproj) {
    b_l0 = *(const bf16x8*)&Brl[kb];
    b_l1 = *(const bf16x8*)&Brl[kb + 8];
  }

  for (int kc = 0; kc < H; kc += 32) {
    const int bfx = (kc >> 5) & 1;
    *(ushort4*)&Ahs[bfx][arow][ka] = a_h;
    *(ushort4*)&Als[bfx][arow][ka] = a_l;
    *(bf16x8*)&Bhs[bfx][brow][kb] = b_h0;
    *(bf16x8*)&Bhs[bfx][brow][kb + 8] = b_h1;
    if (isproj) {
      *(bf16x8*)&Bls[bfx][brow][kb] = b_l0;
      *(bf16x8*)&Bls[bfx][brow][kb + 8] = b_l1;
    }
    __syncthreads();  // single barrier; buf^1 writers are a full iter behind
    if (kc + 32 < H) {  // prefetch next chunk -- in flight during MFMA below
      a_h = *(const ushort4*)&Arh[kc + 32 + ka];
      a_l = *(const ushort4*)&Arl[kc + 32 + ka];
      b_h0 = *(const bf16x8*)&Brh[kc + 32 + kb];
      b_h1 = *(const bf16x8*)&Brh[kc + 32 + kb + 8];
      if (isproj) {
        b_l0 = *(const bf16x8*)&Brl[kc + 32 + kb];
        b_l1 = *(const bf16x8*)&Brl[kc + 32 + kb + 8];
      }
    }
    bf16x8 afh[2], bfh[2];
#pragma unroll
    for (int i = 0; i < 2; ++i) {
      afh[i] = *(const bf16x8*)&Ahs[bfx][i * 16 + fm][quad * 8];
      bfh[i] = *(const bf16x8*)&Bhs[bfx][wn + i * 16 + fm][quad * 8];
    }
    if (isproj) {
      bf16x8 afl[2], bfl[2];
#pragma unroll
      for (int i = 0; i < 2; ++i) {
        afl[i] = *(const bf16x8*)&Als[bfx][i * 16 + fm][quad * 8];
        bfl[i] = *(const bf16x8*)&Bls[bfx][wn + i * 16 + fm][quad * 8];
      }
#pragma unroll
      for (int i = 0; i < 2; ++i)
#pragma unroll
        for (int j = 0; j < 2; ++j) {  // per-acc order hh,hl,lh == rounds 7-9
          acc[i][j] = __builtin_amdgcn_mfma_f32_16x16x32_bf16(afh[i], bfh[j], acc[i][j], 0, 0, 0);
          acc[i][j] = __builtin_amdgcn_mfma_f32_16x16x32_bf16(afh[i], bfl[j], acc[i][j], 0, 0, 0);
          acc[i][j] = __builtin_amdgcn_mfma_f32_16x16x32_bf16(afl[i], bfh[j], acc[i][j], 0, 0, 0);
        }
    } else {
#pragma unroll
      for (int i = 0; i < 2; ++i)
#pragma unroll
        for (int j = 0; j < 2; ++j)
          acc[i][j] = __builtin_amdgcn_mfma_f32_16x16x32_bf16(afh[i], bfh[j], acc[i][j], 0, 0, 0);
    }
  }
#pragma unroll
  for (int j = 0; j < 2; ++j) {
    const int col = n0 + wn + j * 16 + fm;
    if (col < 2 * H) {          // hij: CSCALE*(acc + proj bias)
      const float bias = (col < H) ? Wa_b[col] : Ua_b[col - H];
#pragma unroll
      for (int i = 0; i < 2; ++i)
#pragma unroll
        for (int rg = 0; rg < 4; ++rg) {
          const int row = m0 + i * 16 + quad * 4 + rg;
          hij[(size_t)row * 1536 + col] = CSCALE * (acc[i][j][rg] + bias);
        }
    } else if (col < 3 * H) {   // dp: + dense_b, bf16
      const int o = col - 2 * H;
      const float bias = dense_b[o];
#pragma unroll
      for (int i = 0; i < 2; ++i)
#pragma unroll
        for (int rg = 0; rg < 4; ++rg) {
          const int row = m0 + i * 16 + quad * 4 + rg;
          dpb[(size_t)row * H + o] = (__bf16)(acc[i][j][rg] + bias);
        }
    } else {                    // hp: raw, bf16
      const int o = col - 3 * H;
#pragma unroll
      for (int i = 0; i < 2; ++i)
#pragma unroll
        for (int rg = 0; rg < 4; ++rg) {
          const int row = m0 + i * 16 + quad * 4 + rg;
          hpb[(size_t)row * H + o] = (__bf16)acc[i][j][rg];
        }
    }
  }
}

// ---------------------------------------------------------------------------
// Stage 2: partial[ch][b,a,c] = Sva_ch + sum_{h in ch} (-2 va[h]) * rcp(2^(xi+xj)+1)
// AT ROOFLINE: 36.6 cyc/wave-elem-group vs ~32-cyc transcendental-pipe floor;
// occupancy doubling measured neutral. Unchanged.
__global__ __launch_bounds__(256) void biaffine4(
    const float* __restrict__ hij, const float* __restrict__ va,
    float* __restrict__ partials) {
  __shared__ __align__(16) float his[2][16][34];
  __shared__ __align__(16) float hjs[2][16][34];
  __shared__ __align__(16) float vas2[96];
  __shared__ float svas;
  const int z = blockIdx.z;
  const int b = z >> 3;
  const int ch = z & 7;
  const int hc0 = ch * 96;
  const int a0 = blockIdx.y * 32;
  const int c0 = blockIdx.x * 32;
  const int t = threadIdx.x;
  if (t < 96) vas2[t] = -2.f * va[hc0 + t];
  __syncthreads();
  if (t < 64) {
    float s = vas2[t] + ((t < 32) ? vas2[t + 64] : 0.f);
#pragma unroll
    for (int off = 32; off > 0; off >>= 1) s += __shfl_xor(s, off);
    if (t == 0) svas = -0.5f * s;
  }
  const int lh = t & 15;
  const int lr = t >> 4;
  const int ca = (t & 15) * 2;
  const int aa = (t >> 4) * 2;
  const float* pi0b = hij + (size_t)(b * S + c0 + lr) * 1536 + hc0 + lh;
  const float* pi1b = hij + (size_t)(b * S + c0 + lr + 16) * 1536 + hc0 + lh;
  const float* pj0b = hij + (size_t)(b * S + a0 + lr) * 1536 + 768 + hc0 + lh;
  const float* pj1b = hij + (size_t)(b * S + a0 + lr + 16) * 1536 + 768 + hc0 + lh;
  float acc00 = 0.f, acc01 = 0.f, acc10 = 0.f, acc11 = 0.f;

  float pi0 = pi0b[0], pi1 = pi1b[0], pj0 = pj0b[0], pj1 = pj1b[0];
  for (int hr = 0; hr < 96; hr += 16) {
    const int bf = (hr >> 4) & 1;
    his[bf][lh][lr]      = pi0;
    his[bf][lh][lr + 16] = pi1;
    hjs[bf][lh][lr]      = pj0;
    hjs[bf][lh][lr + 16] = pj1;
    __syncthreads();
    if (hr + 16 < 96) {
      pi0 = pi0b[hr + 16]; pi1 = pi1b[hr + 16];
      pj0 = pj0b[hr + 16]; pj1 = pj1b[hr + 16];
    }
    float vreg[16];
    *(float4*)&vreg[0]  = *(const float4*)&vas2[hr + 0];
    *(float4*)&vreg[4]  = *(const float4*)&vas2[hr + 4];
    *(float4*)&vreg[8]  = *(const float4*)&vas2[hr + 8];
    *(float4*)&vreg[12] = *(const float4*)&vas2[hr + 12];
#pragma unroll
    for (int h = 0; h < 16; ++h) {
      float v = vreg[h];
      float2 xi = *(const float2*)&his[bf][h][ca];
      float2 xj = *(const float2*)&hjs[bf][h][aa];
      acc00 = fmaf(v, rcp_native(exp2_native(xi.x + xj.x) + 1.f), acc00);
      acc01 = fmaf(v, rcp_native(exp2_native(xi.y + xj.x) + 1.f), acc01);
      acc10 = fmaf(v, rcp_native(exp2_native(xi.x + xj.y) + 1.f), acc10);
      acc11 = fmaf(v, rcp_native(exp2_native(xi.y + xj.y) + 1.f), acc11);
    }
  }
  const float sv = svas;
  float* pout = partials + (size_t)ch * (NB * S * S);
  float2 r0 = {acc00 + sv, acc01 + sv};
  float2 r1 = {acc10 + sv, acc11 + sv};
  *(float2*)&pout[(b * S + a0 + aa) * S + c0 + ca]     = r0;
  *(float2*)&pout[(b * S + a0 + aa + 1) * S + c0 + ca] = r1;
}

// ---------------------------------------------------------------------------
// Stage 3 (topk + type-logits fused): combine 8 partials -> logits + top-4,
// then out_type[row,k,l] = fc_b[l] + sum_o tanh(dp[row,o]+hp[b,cand,o])*fc_w[l,o]
__global__ __launch_bounds__(64) void topk_final(
    const float* __restrict__ partials, const __bf16* __restrict__ dpb,
    const __bf16* __restrict__ hpb, const float* __restrict__ fc_w,
    const float* __restrict__ fc_b, float* __restrict__ logits,
    float* __restrict__ out_type) {
  const int row = blockIdx.x;  // b*S + a
  const int lane = threadIdx.x;
  const int P = NB * S * S;
  float v[4];
#pragma unroll
  for (int j = 0; j < 4; ++j) {
    int c = row * S + j * 64 + lane;
    float s0 = partials[c]         + partials[c + P];
    float s1 = partials[c + 2 * P] + partials[c + 3 * P];
    float s2 = partials[c + 4 * P] + partials[c + 5 * P];
    float s3 = partials[c + 6 * P] + partials[c + 7 * P];
    v[j] = (s0 + s1) + (s2 + s3);
    logits[c] = v[j];
  }
  int cand[TOPK];
#pragma unroll
  for (int k = 0; k < TOPK; ++k) {
    float bestv = v[0];
    int besti = lane;
#pragma unroll
    for (int j = 1; j < 4; ++j) {
      int c = j * 64 + lane;
      if (v[j] > bestv) { bestv = v[j]; besti = c; }
    }
#pragma unroll
    for (int off = 32; off > 0; off >>= 1) {
      float ov = __shfl_xor(bestv, off);
      int oi = __shfl_xor(besti, off);
      if (ov > bestv || (ov == bestv && oi < besti)) { bestv = ov; besti = oi; }
    }
    int mj = besti >> 6, ml = besti & 63;
#pragma unroll
    for (int j = 0; j < 4; ++j)
      if (lane == ml && j == mj) v[j] = -3.402823466e38f;
    cand[k] = besti;
  }
  // type logits for the 4 candidates
  const __bf16* dp = dpb + (size_t)row * H;
  const int brow0 = (row >> 8) << 8;  // b*S
#pragma unroll
  for (int k = 0; k < TOPK; ++k) {
    const __bf16* hp = hpb + (size_t)(brow0 + cand[k]) * H;
    float acc[L] = {};
#pragma unroll
    for (int j = 0; j < 3; ++j) {
      const int o = j * 256 + lane * 4;
      bf16x4 dv = *(const bf16x4*)&dp[o];
      bf16x4 hv = *(const bf16x4*)&hp[o];
      float hd[4];
#pragma unroll
      for (int c = 0; c < 4; ++c)
        hd[c] = fast_tanh((float)dv[c] + (float)hv[c]);
#pragma unroll
      for (int l = 0; l < L; ++l) {
        float4 w = *(const float4*)&fc_w[l * H + o];
        acc[l] = fmaf(hd[0], w.x, acc[l]);
        acc[l] = fmaf(hd[1], w.y, acc[l]);
        acc[l] = fmaf(hd[2], w.z, acc[l]);
        acc[l] = fmaf(hd[3], w.w, acc[l]);
      }
    }
#pragma unroll
    for (int l = 0; l < L; ++l)
#pragma unroll
      for (int off = 32; off > 0; off >>= 1) acc[l] += __shfl_xor(acc[l], off);
    if (lane == 0) {
#pragma unroll
      for (int l = 0; l < L; ++l)
        out_type[((size_t)row * TOPK + k) * L + l] = acc[l] + fc_b[l];
    }
  }
}

// ---------------------------------------------------------------------------
extern "C" void kernel_launch(void* const* d_in, const int* in_sizes, int n_in,
                              void* d_out, int out_size, void* d_ws, size_t ws_size,
                              hipStream_t stream) {
  const float* pooled  = (const float*)d_in[0];
  const float* Wa_w    = (const float*)d_in[1];
  const float* Wa_b    = (const float*)d_in[2];
  const float* Ua_w    = (const float*)d_in[3];
  const float* Ua_b    = (const float*)d_in[4];
  const float* va_w    = (const float*)d_in[5];
  const float* dense_w = (const float*)d_in[6];
  const float* dense_b = (const float*)d_in[7];
  const float* fc_w    = (const float*)d_in[8];
  const float* fc_b    = (const float*)d_in[9];

  float* logits   = (float*)d_out;            // (4,256,256)
  float* out_type = logits + NB * S * S;      // (4,256,4,4)

  // ws layout, 20 MB (< 22.8 MB known-good). Temporal aliasing: Wh/Wl/Drow
  // live inside the partials region -- dead after mega, before biaffine
  // writes partials. Ah/Al/dpb/hpb are in non-aliased space.
  float*  hij      = (float*)d_ws;                   // [0, 1572864) f
  float*  partials = hij + 1572864;                  // [.., +2097152) f (8 MB)
  __bf16* Wh       = (__bf16*)partials;              //   1179648 bf16 (alias)
  __bf16* Wl       = Wh + 1179648;                   //   1179648 bf16 (alias)
  __bf16* Drow     = Wl + 1179648;                   //   1179648 bf16 (alias, 6.75/8 MB)
  __bf16* dpb      = (__bf16*)(partials + 2097152);  // 786432 bf16
  __bf16* hpb      = dpb + 786432;                   // 786432 bf16
  __bf16* Ah       = hpb + 786432;                   // 786432 bf16
  __bf16* Al       = Ah + 786432;                    // 786432 bf16

  cvt_kernel<<<dim3(3072), 256, 0, stream>>>(pooled, Wa_w, Ua_w, dense_w,
                                             Ah, Al, Wh, Wl, Drow);
  mega_mfma<<<dim3(32, 24), 256, 0, stream>>>(Ah, Al, Wh, Wl, Drow,
                                              Wa_b, Ua_b, dense_b,
                                              hij, dpb, hpb);
  biaffine4<<<dim3(8, 8, NB * NH), 256, 0, stream>>>(hij, va_w, partials);
  topk_final<<<dim3(1024), 64, 0, stream>>>(partials, dpb, hpb, fc_w, fc_b,
                                            logits, out_type);
}